// Round 3
// baseline (754.865 us; speedup 1.0000x reference)
//
#include <hip/hip_runtime.h>
#include <math.h>

// StackedLSTM: B=2048, T=2048, D=H=6, 2 layers, softmax(h_last) -> [2048, 6] fp32.
//
// R3 mapping: ONE batch element per wave (lanes 0-31 active; 2048 waves = 2/SIMD).
//   l = lane>>4 (layer), q = lane&15, j = q>>1 (unit), p = q&1 (gate pair).
//   p=0 lanes own rows (i,f) of unit j; p=1 own (g,o). Layer 1 runs one
//   timestep behind layer 0 in the same instruction stream.
//
// R3 change vs R2: h broadcast via v_readlane -> SGPRs (VALU pipe, ~8 cyc)
//   instead of ds_bpermute (LDS pipe, ~120 cyc). R2 spent ~300 cyc/step
//   waiting on lgkmcnt for 12 bpermutes. One batch/wave makes h wave-uniform,
//   which is what legalizes the SGPR path. FMA takes one SGPR operand, so
//   each gate row = 3 chains: dot(x,wx) + dot(s_h0,wh0) + dot(s_h1,wh1),
//   with zero-padded weights selecting the layer's live terms (no per-lane
//   operand selection on the critical path).
// Also: exp prescales folded into weights (exp2 domain, negated so
//   sigmoid = rcp(1+exp2(s))), x prefetched 1 step ahead into VGPRs,
//   layer-1 phantom-step cleanup moved to a uniform t==1 branch.

#define TSTEPS 2048
#define LOG2E 1.442695040889f

__device__ __forceinline__ float fast_rcp(float v) { return __builtin_amdgcn_rcpf(v); }

#if __has_builtin(__builtin_amdgcn_exp2f)
#define EXP2F(x) __builtin_amdgcn_exp2f(x)
#else
#define EXP2F(x) __expf((x) * 0.69314718056f)
#endif

__device__ __forceinline__ float rdlane_f(float v, int srclane) {
    return __int_as_float(__builtin_amdgcn_readlane(__float_as_int(v), srclane));
}

// lane ^ 1 exchange: quad_perm [1,0,3,2] = 0xB1
__device__ __forceinline__ float dpp_xor1_f(float v) {
    return __int_as_float(__builtin_amdgcn_mov_dpp(__float_as_int(v), 0xB1, 0xF, 0xF, true));
}

__global__ __launch_bounds__(64, 1)
void stacked_lstm_kernel(const float* __restrict__ x,
                         const float* __restrict__ Wih0, const float* __restrict__ Whh0,
                         const float* __restrict__ bih0, const float* __restrict__ bhh0,
                         const float* __restrict__ Wih1, const float* __restrict__ Whh1,
                         const float* __restrict__ bih1, const float* __restrict__ bhh1,
                         float* __restrict__ out)
{
    __shared__ __align__(16) float Xs[2][192];   // [buf][32 steps * 6 floats]

    const int lane = threadIdx.x;
    if (lane >= 32) return;                      // one batch element per wave

    const int l = lane >> 4;          // layer 0/1
    const int q = lane & 15;
    const int j = q >> 1;             // unit (0..7; 6,7 dummy mirrors of 5)
    const int p = q & 1;              // 0 -> (i,f) rows; 1 -> (g,o) rows
    const int jc = (j < 6) ? j : 5;
    const long b = (long)blockIdx.x;

    // ---- per-lane weights, pre-scaled into exp2 domain, zero-padded per term ----
    const float* Wih = l ? Wih1 : Wih0;
    const float* Whh = l ? Whh1 : Whh0;
    const float* bih = l ? bih1 : bih0;
    const float* bhh = l ? bhh1 : bhh0;
    // PyTorch gate-row order: i=0..5, f=6..11, g=12..17, o=18..23
    const int rA = p * 12 + jc;       // p=0: i-row ; p=1: g-row
    const int rB = rA + 6;            // p=0: f-row ; p=1: o-row
    // sigmoid(v) = rcp(1+exp2(-LOG2E*v)); tanh(v) = 2*rcp(1+exp2(-2*LOG2E*v)) - 1
    const float scA = p ? (-2.0f * LOG2E) : (-LOG2E);
    const float scB = -LOG2E;
    const float cA = p ? 2.0f : 1.0f;
    const float dA = p ? -1.0f : 0.0f;

    float wxA[6], wh0A[6], wh1A[6], wxB[6], wh0B[6], wh1B[6];
#pragma unroll
    for (int k = 0; k < 6; ++k) {
        float aih = Wih[rA * 6 + k] * scA, ahh = Whh[rA * 6 + k] * scA;
        float bih_ = Wih[rB * 6 + k] * scB, bhh_ = Whh[rB * 6 + k] * scB;
        // L0: input term = x, recurrent = h0.  L1: input = h0, recurrent = h1.
        wxA[k]  = l ? 0.0f : aih;
        wh0A[k] = l ? aih  : ahh;
        wh1A[k] = l ? ahh  : 0.0f;
        wxB[k]  = l ? 0.0f : bih_;
        wh0B[k] = l ? bih_ : bhh_;
        wh1B[k] = l ? bhh_ : 0.0f;
    }
    const float bAs = (bih[rA] + bhh[rA]) * scA;
    const float bBs = (bih[rB] + bhh[rB]) * scB;

    // ---- x staging: 32 steps (192 floats) double-buffered in LDS ----
    const float* xb = x + b * (TSTEPS * 6);
    float4 pre0, pre1;
    auto LOADBLK = [&](int blk) {
        const float4* xv = (const float4*)(xb + blk * 192);
        pre0 = xv[lane];
        if (lane < 16) pre1 = xv[32 + lane];
    };
    auto WRITEBLK = [&](int buf) {
        float4* dst = (float4*)&Xs[buf][0];
        dst[lane] = pre0;
        if (lane < 16) dst[32 + lane] = pre1;
    };

    LOADBLK(0);
    WRITEBLK(0);
    LOADBLK(1);
    __builtin_amdgcn_wave_barrier();

    // preload x_0 (wave-uniform values in VGPRs)
    float2 xc0 = *(const float2*)&Xs[0][0];
    float2 xc1 = *(const float2*)&Xs[0][2];
    float2 xc2 = *(const float2*)&Xs[0][4];

    float hv = 0.0f;   // own unit's h (identical on both pair lanes)
    float c  = 0.0f;

    // T+1 iterations: at iter t, layer0 computes step t, layer1 computes step t-1.
    for (int t = 0; t <= TSTEPS; ++t) {
        // gather previous-step h into SGPRs (VALU pipe, no LDS latency)
        float h0[6], h1[6];
#pragma unroll
        for (int k = 0; k < 6; ++k) {
            h0[k] = rdlane_f(hv, 2 * k);        // layer-0 h, unit k
            h1[k] = rdlane_f(hv, 16 + 2 * k);   // layer-1 h, unit k
        }
        if (t == 1) {
            // iter 0's layer-1 output was a phantom (nonexistent step -1)
#pragma unroll
            for (int k = 0; k < 6; ++k) h1[k] = 0.0f;
            c = l ? 0.0f : c;
        }

        const int row = t & 31;
        if (row == 31) {   // stage next block one iter early (uniform branch)
            const int nblk = (t + 1) >> 5;
            if (nblk <= 63) {
                WRITEBLK(nblk & 1);
                if (nblk + 1 <= 63) LOADBLK(nblk + 1);
            }
            __builtin_amdgcn_wave_barrier();
        }

        // prefetch x_{t+1}; its LDS latency overlaps this step's chain
        const int tn = t + 1;
        const float* xp = &Xs[(tn >> 5) & 1][(tn & 31) * 6];
        float2 nx0 = *(const float2*)(xp + 0);
        float2 nx1 = *(const float2*)(xp + 2);
        float2 nx2 = *(const float2*)(xp + 4);

        const float xv6[6] = {xc0.x, xc0.y, xc1.x, xc1.y, xc2.x, xc2.y};

        // 6 independent FMA chains (A,B rows x {x, h0, h1} terms)
        float sAx = bAs, sA0 = 0.0f, sA1 = 0.0f;
        float sBx = bBs, sB0 = 0.0f, sB1 = 0.0f;
#pragma unroll
        for (int k = 0; k < 6; ++k) {
            sAx = fmaf(xv6[k], wxA[k], sAx);
            sA0 = fmaf(h0[k], wh0A[k], sA0);
            sA1 = fmaf(h1[k], wh1A[k], sA1);
            sBx = fmaf(xv6[k], wxB[k], sBx);
            sB0 = fmaf(h0[k], wh0B[k], sB0);
            sB1 = fmaf(h1[k], wh1B[k], sB1);
        }
        const float sA = (sAx + sA0) + sA1;   // already exp2-domain, negated
        const float sB = (sBx + sB0) + sB1;

        const float eA = EXP2F(sA);
        const float eB = EXP2F(sB);
        const float rcA = fast_rcp(1.0f + eA);
        const float rcB = fast_rcp(1.0f + eB);
        const float aA = fmaf(cA, rcA, dA);   // p=0: sigmoid(i) ; p=1: tanh(g)
        const float aB = rcB;                  // sigmoid (f or o)

        // pair exchange (lane^1) via DPP
        const float xA = dpp_xor1_f(aA);
        const float xB = dpp_xor1_f(aB);
        const float ig = aA * xA;              // i*g (identical on both pair lanes)
        const float gf = p ? xB : aB;
        const float go = p ? aB : xB;

        const float cn = fmaf(gf, c, ig);
        const float m2 = cn * (2.0f * LOG2E);
        const float e2 = EXP2F(m2);
        const float th = fmaf(-2.0f, fast_rcp(1.0f + e2), 1.0f);  // tanh(cn)
        hv = go * th;
        c  = cn;

        xc0 = nx0; xc1 = nx1; xc2 = nx2;
    }

    // ---- epilogue: h1_last lives on lanes 16+2k; softmax, store lanes 0..5 ----
    const float v0 = rdlane_f(hv, 16), v1 = rdlane_f(hv, 18), v2 = rdlane_f(hv, 20);
    const float v3 = rdlane_f(hv, 22), v4 = rdlane_f(hv, 24), v5 = rdlane_f(hv, 26);
    const float mx = fmaxf(fmaxf(fmaxf(v0, v1), fmaxf(v2, v3)), fmaxf(v4, v5));
    const float e0 = __expf(v0 - mx), e1 = __expf(v1 - mx), e2_ = __expf(v2 - mx);
    const float e3 = __expf(v3 - mx), e4 = __expf(v4 - mx), e5 = __expf(v5 - mx);
    const float sum = ((e0 + e1) + (e2_ + e3)) + (e4 + e5);
    const float r = fast_rcp(sum);
    if (lane < 6) {
        const float mine = (lane == 0) ? e0 : (lane == 1) ? e1 : (lane == 2) ? e2_
                         : (lane == 3) ? e3 : (lane == 4) ? e4 : e5;
        out[b * 6 + lane] = mine * r;
    }
}

extern "C" void kernel_launch(void* const* d_in, const int* in_sizes, int n_in,
                              void* d_out, int out_size, void* d_ws, size_t ws_size,
                              hipStream_t stream) {
    (void)in_sizes; (void)n_in; (void)d_ws; (void)ws_size; (void)out_size;
    const float* x    = (const float*)d_in[0];
    const float* Wih0 = (const float*)d_in[1];
    const float* Whh0 = (const float*)d_in[2];
    const float* bih0 = (const float*)d_in[3];
    const float* bhh0 = (const float*)d_in[4];
    const float* Wih1 = (const float*)d_in[5];
    const float* Whh1 = (const float*)d_in[6];
    const float* bih1 = (const float*)d_in[7];
    const float* bhh1 = (const float*)d_in[8];
    float* outp = (float*)d_out;

    // 1 batch element per wave: 2048 blocks of 64 threads (lanes 32-63 exit)
    // = 2048 waves = 2 waves/SIMD machine-wide.
    stacked_lstm_kernel<<<2048, 64, 0, stream>>>(
        x, Wih0, Whh0, bih0, bhh0, Wih1, Whh1, bih1, bhh1, outp);
}